// Round 1
// baseline (1095.844 us; speedup 1.0000x reference)
//
#include <hip/hip_runtime.h>
#include <math.h>

#define DIM 24
#define HID 256
#define NLO 276
#define NSAMP 4096
// output layout: M [4096*576] | c [4096*24] | g [4096*24]
#define C_OFF 2359296
#define G_OFF 2457600

__device__ __forceinline__ float leaky(float x){ return x > 0.f ? x : 0.01f*x; }

// ---------------- Kernel 1: trunk + heads + L + M + g + u ----------------
__global__ __launch_bounds__(256) void k1_fwd(
    const float* __restrict__ q, const float* __restrict__ qd,
    const float* __restrict__ W1, const float* __restrict__ b1,
    const float* __restrict__ W2, const float* __restrict__ b2,
    const float* __restrict__ WG, const float* __restrict__ bG,
    const float* __restrict__ WLd, const float* __restrict__ bLd,
    const float* __restrict__ WLo, const float* __restrict__ bLo,
    float* __restrict__ H1, float* __restrict__ H2, float* __restrict__ H3,
    float* __restrict__ Lws, float* __restrict__ Uws, float* __restrict__ out)
{
  const int n = blockIdx.x, t = threadIdx.x;
  __shared__ float q_s[DIM], qd_s[DIM], h1_s[HID], h2_s[HID], h3_s[DIM], lo_s[NLO], L_s[DIM*DIM];
  if (t < DIM){ q_s[t] = q[n*DIM+t]; qd_s[t] = qd[n*DIM+t]; }
  __syncthreads();
  // h1 = leaky(W1 q + b1), thread t -> unit t
  {
    float s = b1[t];
    const float* w = W1 + t*DIM;
    #pragma unroll
    for (int d = 0; d < DIM; ++d) s += w[d]*q_s[d];
    s = leaky(s);
    h1_s[t] = s; H1[n*HID+t] = s;
  }
  __syncthreads();
  // h2 = leaky(W2 h1 + b2)
  {
    float s = b2[t];
    const float4* w = (const float4*)(W2 + t*HID);
    const float4* h = (const float4*)h1_s;
    #pragma unroll 4
    for (int k = 0; k < HID/4; ++k){ float4 a = w[k], b = h[k]; s += a.x*b.x + a.y*b.y + a.z*b.z + a.w*b.w; }
    s = leaky(s);
    h2_s[t] = s; H2[n*HID+t] = s;
  }
  __syncthreads();
  // heads: idx 0..23 -> h3 (pre-softplus), 24..47 -> g, 48..323 -> Lo
  for (int idx = t; idx < 2*DIM+NLO; idx += 256){
    const float* w; float bb;
    if (idx < DIM)        { w = WLd + idx*HID;         bb = bLd[idx]; }
    else if (idx < 2*DIM) { w = WG  + (idx-DIM)*HID;   bb = bG[idx-DIM]; }
    else                  { w = WLo + (idx-2*DIM)*HID; bb = bLo[idx-2*DIM]; }
    float acc = bb;
    const float4* wv = (const float4*)w; const float4* h = (const float4*)h2_s;
    #pragma unroll 4
    for (int k = 0; k < HID/4; ++k){ float4 a = wv[k], b = h[k]; acc += a.x*b.x + a.y*b.y + a.z*b.z + a.w*b.w; }
    if (idx < DIM)        { h3_s[idx] = acc; H3[n*DIM+idx] = acc; }
    else if (idx < 2*DIM) { out[G_OFF + n*DIM + (idx-DIM)] = acc; }
    else                  { lo_s[idx-2*DIM] = acc; }
  }
  __syncthreads();
  // L: diag = softplus(h3), strict lower = Lo (row-major tril order p = r(r-1)/2+c)
  for (int idx = t; idx < DIM*DIM; idx += 256){
    int r = idx/DIM, c = idx%DIM; float v = 0.f;
    if (r == c){ float x = h3_s[r]; v = fmaxf(x, 0.f) + log1pf(expf(-fabsf(x))); }
    else if (r > c) v = lo_s[r*(r-1)/2 + c];
    L_s[idx] = v; Lws[n*DIM*DIM + idx] = v;
  }
  __syncthreads();
  // M = L L^T + 1e-9 I ; u[c] = sum_r qd[r] L[r,c]
  for (int idx = t; idx < DIM*DIM; idx += 256){
    int r = idx/DIM, c = idx%DIM, km = min(r, c);
    float acc = (r == c) ? 1e-9f : 0.f;
    for (int k = 0; k <= km; ++k) acc += L_s[r*DIM+k]*L_s[c*DIM+k];
    out[n*DIM*DIM + idx] = acc;
  }
  if (t < DIM){
    float acc = 0.f;
    for (int r = t; r < DIM; ++r) acc += qd_s[r]*L_s[r*DIM+t];
    Uws[n*DIM+t] = acc;
  }
}

// ---------------- Kernel 2: Jacobian chain + c ----------------
__global__ __launch_bounds__(256) void k2_jac(
    const float* __restrict__ q_dot,
    const float* __restrict__ W1, const float* __restrict__ W2,
    const float* __restrict__ WLd, const float* __restrict__ WLo,
    const float* __restrict__ H1, const float* __restrict__ H2, const float* __restrict__ H3,
    const float* __restrict__ Lws, const float* __restrict__ Uws,
    float* __restrict__ out)
{
  const int n = blockIdx.x, t = threadIdx.x;
  __shared__ float J2_s[HID*DIM];      // 6144 f
  __shared__ float buf_s[NLO*DIM];     // 6624 f: first holds A=J1 (6144), then dlo_dq flat [o*24+dd]
  __shared__ float dld_s[DIM*DIM];     // dld_dq [i][dd]
  __shared__ float L_s[DIM*DIM];
  __shared__ float dLdt_s[DIM*DIM];
  __shared__ float qd_s[DIM], dlo_dt_s[NLO], dld_dt_s[DIM], w1_s[DIM], u_s[DIM];

  if (t < DIM){ qd_s[t] = q_dot[n*DIM+t]; u_s[t] = Uws[n*DIM+t]; }
  // A = dR1 .* W1  (row k scaled by dR1[k]); W1 flat [k*24+dd] matches buf layout
  for (int idx = t; idx < HID*DIM; idx += 256){
    int k = idx/DIM;
    float dr = H1[n*HID+k] > 0.f ? 1.f : -0.01f;   // NEG = -0.01 (faithful)
    buf_s[idx] = dr * W1[idx];
  }
  for (int idx = t; idx < DIM*DIM; idx += 256) L_s[idx] = Lws[n*DIM*DIM + idx];
  __syncthreads();

  // Stage D: J2 row t = dR2[t] * (W2[t,:] @ A)
  {
    float acc[DIM];
    #pragma unroll
    for (int d = 0; d < DIM; ++d) acc[d] = 0.f;
    const float4* w2r = (const float4*)(W2 + t*HID);
    for (int k4 = 0; k4 < HID/4; ++k4){
      float4 w = w2r[k4];
      const float* ab = &buf_s[(k4*4)*DIM];
      #pragma unroll
      for (int kk = 0; kk < 4; ++kk){
        float wv = (kk==0)?w.x:(kk==1)?w.y:(kk==2)?w.z:w.w;
        const float4* ar = (const float4*)(ab + kk*DIM);
        #pragma unroll
        for (int d4 = 0; d4 < 6; ++d4){
          float4 a = ar[d4];
          acc[4*d4+0] += wv*a.x; acc[4*d4+1] += wv*a.y;
          acc[4*d4+2] += wv*a.z; acc[4*d4+3] += wv*a.w;
        }
      }
    }
    float dr2 = H2[n*HID+t] > 0.f ? 1.f : -0.01f;
    float4* jr = (float4*)&J2_s[t*DIM];
    #pragma unroll
    for (int d4 = 0; d4 < 6; ++d4){
      float4 v; v.x = dr2*acc[4*d4+0]; v.y = dr2*acc[4*d4+1]; v.z = dr2*acc[4*d4+2]; v.w = dr2*acc[4*d4+3];
      jr[d4] = v;
    }
  }
  __syncthreads();

  // Stage E: rows 0..23 -> dld_dq (sig-scaled), rows 24..299 -> dlo_dq (into buf_s, overwrites A)
  for (int r = t; r < DIM+NLO; r += 256){
    float acc[DIM];
    #pragma unroll
    for (int d = 0; d < DIM; ++d) acc[d] = 0.f;
    const float4* wr = (const float4*)((r < DIM) ? (WLd + r*HID) : (WLo + (r-DIM)*HID));
    for (int k4 = 0; k4 < HID/4; ++k4){
      float4 w = wr[k4];
      const float* jb = &J2_s[(k4*4)*DIM];
      #pragma unroll
      for (int kk = 0; kk < 4; ++kk){
        float wv = (kk==0)?w.x:(kk==1)?w.y:(kk==2)?w.z:w.w;
        const float4* ar = (const float4*)(jb + kk*DIM);
        #pragma unroll
        for (int d4 = 0; d4 < 6; ++d4){
          float4 a = ar[d4];
          acc[4*d4+0] += wv*a.x; acc[4*d4+1] += wv*a.y;
          acc[4*d4+2] += wv*a.z; acc[4*d4+3] += wv*a.w;
        }
      }
    }
    if (r < DIM){
      float sg = 1.f/(1.f + expf(-H3[n*DIM+r]));
      #pragma unroll
      for (int d = 0; d < DIM; ++d) dld_s[r*DIM+d] = sg*acc[d];
    } else {
      float* dst = &buf_s[(r-DIM)*DIM];
      #pragma unroll
      for (int d = 0; d < DIM; ++d) dst[d] = acc[d];
    }
  }
  __syncthreads();

  // dld_dt / dlo_dt (within-sample q_dot contraction)
  if (t < DIM){
    float acc = 0.f;
    #pragma unroll
    for (int d = 0; d < DIM; ++d) acc += dld_s[t*DIM+d]*qd_s[d];
    dld_dt_s[t] = acc;
  }
  for (int o = t; o < NLO; o += 256){
    float acc = 0.f;
    #pragma unroll
    for (int d = 0; d < DIM; ++d) acc += buf_s[o*DIM+d]*qd_s[d];
    dlo_dt_s[o] = acc;
  }
  __syncthreads();
  // assemble dL_dt
  for (int idx = t; idx < DIM*DIM; idx += 256){
    int r = idx/DIM, c = idx%DIM;
    float v = 0.f;
    if (r == c) v = dld_dt_s[r]; else if (r > c) v = dlo_dt_s[r*(r-1)/2 + c];
    dLdt_s[idx] = v;
  }
  __syncthreads();
  // w1[k] = sum_j qd[j] dLdt[j,k]
  if (t < DIM){
    float acc = 0.f;
    #pragma unroll
    for (int j = 0; j < DIM; ++j) acc += qd_s[j]*dLdt_s[j*DIM+t];
    w1_s[t] = acc;
  }
  __syncthreads();
  // c_i = sum_k (L[i,k] w1[k] + dLdt[i,k] u_n[k]) - sum_c u_m[c] v_c
  // (quad = 2*sum; c subtracts 0.5*quad -> subtract the plain sum)
  if (t < DIM){
    const int i = t;
    float cs = 0.f;
    #pragma unroll
    for (int k = 0; k < DIM; ++k) cs += L_s[i*DIM+k]*w1_s[k] + dLdt_s[i*DIM+k]*u_s[k];
    const int m = (n*DIM + i) & (NSAMP-1);   // faithful cross-sample index (n*24+qi) % 4096
    const float* qdm = q_dot + m*DIM;
    const float* um  = Uws   + m*DIM;
    const float* vb  = &buf_s[i*NLO];        // vals[i,p] = dlo_flat[i*276+p] (faithful reinterpretation)
    float quad = 0.f;
    for (int c2 = 0; c2 < DIM; ++c2){
      float v = qdm[c2]*dld_s[c2*DIM+i];     // diag: dld_dq[n, c2, i]
      for (int r = c2+1; r < DIM; ++r) v += qdm[r]*vb[r*(r-1)/2 + c2];
      quad += um[c2]*v;
    }
    out[C_OFF + n*DIM + i] = cs - quad;
  }
}

extern "C" void kernel_launch(void* const* d_in, const int* in_sizes, int n_in,
                              void* d_out, int out_size, void* d_ws, size_t ws_size,
                              hipStream_t stream)
{
  const float* q   = (const float*)d_in[0];
  const float* qd  = (const float*)d_in[1];
  const float* W1  = (const float*)d_in[2];
  const float* b1  = (const float*)d_in[3];
  const float* W2  = (const float*)d_in[4];
  const float* b2  = (const float*)d_in[5];
  const float* WG  = (const float*)d_in[6];
  const float* bG  = (const float*)d_in[7];
  const float* WLd = (const float*)d_in[8];
  const float* bLd = (const float*)d_in[9];
  const float* WLo = (const float*)d_in[10];
  const float* bLo = (const float*)d_in[11];
  float* out = (float*)d_out;
  float* ws  = (float*)d_ws;
  // ws layout (floats): H1[4096*256] H2[4096*256] H3[4096*24] L[4096*576] U[4096*24] = 18.6 MB
  float* H1  = ws;
  float* H2  = ws + 1048576;
  float* H3  = ws + 2097152;
  float* Lws = ws + 2195456;
  float* Uws = ws + 4554752;
  k1_fwd<<<NSAMP, 256, 0, stream>>>(q, qd, W1, b1, W2, b2, WG, bG, WLd, bLd, WLo, bLo,
                                    H1, H2, H3, Lws, Uws, out);
  k2_jac<<<NSAMP, 256, 0, stream>>>(qd, W1, W2, WLd, WLo, H1, H2, H3, Lws, Uws, out);
}

// Round 2
// 710.054 us; speedup vs baseline: 1.5433x; 1.5433x over previous
//
#include <hip/hip_runtime.h>
#include <math.h>

#define DIM 24
#define HID 256
#define NLO 276
#define NSAMP 4096
// output layout: M [4096*576] | c [4096*24] | g [4096*24]
#define C_OFF 2359296
#define G_OFF 2457600

// workspace layout (float offsets)
#define OFF_W2T 0          // [k*256 + i] = W2[i,k]            65536
#define OFF_WHT 65536      // [k*328 + c] heads^T (Ld|G|Lo)    83968
#define OFF_WET 149504     // [k*320 + c] stageE^T (Ld|Lo|0)   81920
#define OFF_W1T 231424     // [d*256 + i] = W1[i,d]            6144
#define OFF_REC 237568     // per-sample record, 640 floats:
                           // [0..16) msk1/msk2 (16 u32), [16..40) sig, [40..64) u, [64..640) L
#define REC_STRIDE 640

__device__ __forceinline__ float leaky(float x){ return x > 0.f ? x : 0.01f*x; }

// ---------------- Kernel 0: weight transposes / packing ----------------
__global__ __launch_bounds__(256) void k0_prep(
    const float* __restrict__ W1, const float* __restrict__ W2,
    const float* __restrict__ WG, const float* __restrict__ WLd,
    const float* __restrict__ WLo, float* __restrict__ ws)
{
  const int tid = blockIdx.x*256 + threadIdx.x;
  const int nth = gridDim.x*256;
  for (int f = tid; f < 65536; f += nth){            // W2T
    int k = f >> 8, i = f & 255;
    ws[OFF_W2T + f] = W2[i*256 + k];
  }
  for (int f = tid; f < 83968; f += nth){            // WHT stride 328
    int k = f / 328, c = f % 328; float v = 0.f;
    if (c < 24) v = WLd[c*256 + k];
    else if (c < 48) v = WG[(c-24)*256 + k];
    else if (c < 324) v = WLo[(c-48)*256 + k];
    ws[OFF_WHT + f] = v;
  }
  for (int f = tid; f < 81920; f += nth){            // WET stride 320
    int k = f / 320, c = f % 320; float v = 0.f;
    if (c < 24) v = WLd[c*256 + k];
    else if (c < 300) v = WLo[(c-24)*256 + k];
    ws[OFF_WET + f] = v;
  }
  for (int f = tid; f < 6144; f += nth){             // W1T
    int d = f >> 8, i = f & 255;
    ws[OFF_W1T + f] = W1[i*24 + d];
  }
}

// ---------------- Kernel 1: forward trunk + heads + L + M + g + u + record ----------------
__global__ __launch_bounds__(256) void k1_fwd(
    const float* __restrict__ q, const float* __restrict__ qd,
    const float* __restrict__ b1, const float* __restrict__ b2,
    const float* __restrict__ bG, const float* __restrict__ bLd,
    const float* __restrict__ bLo, float* __restrict__ ws,
    float* __restrict__ out)
{
  const int n = blockIdx.x, t = threadIdx.x;
  const int w = t >> 6, l = t & 63;
  const float* W2T = ws + OFF_W2T;
  const float* WHT = ws + OFF_WHT;
  const float* W1T = ws + OFF_W1T;
  float* rec = ws + OFF_REC + (size_t)n*REC_STRIDE;

  __shared__ float q_s[DIM], qd_s[DIM], h1_s[HID], h2_s[HID], h3_s[DIM], lo_s[NLO], L_s[DIM*DIM];
  if (t < DIM){ q_s[t] = q[n*DIM+t]; qd_s[t] = qd[n*DIM+t]; }
  __syncthreads();
  // h1 (coalesced W1T)
  {
    float s = b1[t];
    #pragma unroll
    for (int d = 0; d < DIM; ++d) s += W1T[d*256 + t]*q_s[d];
    unsigned long long b = __ballot(s > 0.f);
    if (l == 0){ ((unsigned*)rec)[2*w] = (unsigned)b; ((unsigned*)rec)[2*w+1] = (unsigned)(b >> 32); }
    h1_s[t] = leaky(s);
  }
  __syncthreads();
  // h2 (coalesced W2T, broadcast h1)
  {
    float s = b2[t];
    const float4* h = (const float4*)h1_s;
    for (int k4 = 0; k4 < HID/4; ++k4){
      float4 hv = h[k4];
      int k = 4*k4;
      s += W2T[(k+0)*256+t]*hv.x + W2T[(k+1)*256+t]*hv.y
         + W2T[(k+2)*256+t]*hv.z + W2T[(k+3)*256+t]*hv.w;
    }
    unsigned long long b = __ballot(s > 0.f);
    if (l == 0){ ((unsigned*)rec)[8+2*w] = (unsigned)b; ((unsigned*)rec)[8+2*w+1] = (unsigned)(b >> 32); }
    h2_s[t] = leaky(s);
  }
  __syncthreads();
  // heads: c<24 -> h3, <48 -> g, <324 -> lo (coalesced WHT)
  for (int c = t; c < 324; c += 256){
    float acc = 0.f;
    const float4* h = (const float4*)h2_s;
    for (int k4 = 0; k4 < HID/4; ++k4){
      float4 hv = h[k4];
      int k = 4*k4;
      acc += WHT[(k+0)*328+c]*hv.x + WHT[(k+1)*328+c]*hv.y
           + WHT[(k+2)*328+c]*hv.z + WHT[(k+3)*328+c]*hv.w;
    }
    if (c < 24){
      acc += bLd[c];
      h3_s[c] = acc;
      rec[16 + c] = 1.f/(1.f + expf(-acc));          // sigmoid for dld scale
    } else if (c < 48){
      out[G_OFF + n*DIM + (c-24)] = acc + bG[c-24];
    } else {
      lo_s[c-48] = acc + bLo[c-48];
    }
  }
  __syncthreads();
  // L
  for (int idx = t; idx < DIM*DIM; idx += 256){
    int r = idx/DIM, c = idx%DIM; float v = 0.f;
    if (r == c){ float x = h3_s[r]; v = fmaxf(x, 0.f) + log1pf(expf(-fabsf(x))); }
    else if (r > c) v = lo_s[r*(r-1)/2 + c];
    L_s[idx] = v; rec[64 + idx] = v;
  }
  __syncthreads();
  // M, u
  for (int idx = t; idx < DIM*DIM; idx += 256){
    int r = idx/DIM, c = idx%DIM, km = min(r, c);
    float acc = (r == c) ? 1e-9f : 0.f;
    for (int k = 0; k <= km; ++k) acc += L_s[r*DIM+k]*L_s[c*DIM+k];
    out[n*DIM*DIM + idx] = acc;
  }
  if (t < DIM){
    float acc = 0.f;
    for (int r = t; r < DIM; ++r) acc += qd_s[r]*L_s[r*DIM+t];
    rec[40 + t] = acc;
  }
}

// ---------------- Kernel 2: Jacobian chain + c ----------------
// wave w owns d-columns [6w, 6w+6); stage D rows l+64j (j<4); stage E rows l+64j (j<5, <300)
__global__ __launch_bounds__(256, 3) void k2_jac(
    const float* __restrict__ q_dot, const float* __restrict__ W1g,
    float* __restrict__ ws, float* __restrict__ out)
{
  const int n = blockIdx.x, t = threadIdx.x;
  const int w = t >> 6, l = t & 63;
  const int c0 = 6*w;
  const float* W2T = ws + OFF_W2T;
  const float* WET = ws + OFF_WET;
  const float* REC = ws + OFF_REC;
  const float* rec = REC + (size_t)n*REC_STRIDE;

  __shared__ float J2_s[HID*DIM];        // later: [0,576)=dld, [576,1152)=dLdt
  __shared__ float dlo_s[NLO*DIM];       // dlo_dq flat [o*24+d]
  __shared__ float dlo_dt_s[NLO];
  __shared__ float qd_s[DIM], u_s[DIM], sig_s[DIM], dld_dt_s[DIM], w1_s[DIM];
  __shared__ unsigned msk_s[16];

  if (t < 16) msk_s[t] = ((const unsigned*)rec)[t];
  if (t < DIM){ sig_s[t] = rec[16+t]; u_s[t] = rec[40+t]; qd_s[t] = q_dot[n*DIM+t]; }
  __syncthreads();

  // ---- Stage D: J2[r, c0..c0+6) = dR2[r] * sum_k W2T[k,r]*dR1[k]*W1[k, c0..] ----
  {
    float acc[4][6];
    #pragma unroll
    for (int j = 0; j < 4; ++j)
      #pragma unroll
      for (int jj = 0; jj < 6; ++jj) acc[j][jj] = 0.f;
    for (int k32 = 0; k32 < 8; ++k32){
      unsigned m1 = msk_s[k32];
      #pragma unroll 8
      for (int kk = 0; kk < 32; ++kk){
        int k = k32*32 + kk;
        float dr1 = ((m1 >> kk) & 1u) ? 1.0f : -0.01f;
        float w1c[6];
        #pragma unroll
        for (int jj = 0; jj < 6; ++jj) w1c[jj] = W1g[k*24 + c0 + jj];
        #pragma unroll
        for (int j = 0; j < 4; ++j){
          float a = W2T[k*256 + l + 64*j] * dr1;
          #pragma unroll
          for (int jj = 0; jj < 6; ++jj) acc[j][jj] = fmaf(a, w1c[jj], acc[j][jj]);
        }
      }
    }
    #pragma unroll
    for (int j = 0; j < 4; ++j){
      int r = l + 64*j;
      unsigned m2 = msk_s[8 + (r >> 5)];
      float dr2 = ((m2 >> (r & 31)) & 1u) ? 1.0f : -0.01f;
      #pragma unroll
      for (int jj = 0; jj < 6; ++jj) J2_s[r*24 + c0 + jj] = dr2*acc[j][jj];
    }
  }
  __syncthreads();

  // ---- Stage E: rows 0..23 dld (sig-scaled), 24..299 dlo ----
  {
    float acc2[5][6];
    #pragma unroll
    for (int j = 0; j < 5; ++j)
      #pragma unroll
      for (int jj = 0; jj < 6; ++jj) acc2[j][jj] = 0.f;
    for (int k4 = 0; k4 < 64; ++k4){
      #pragma unroll
      for (int kk = 0; kk < 4; ++kk){
        int k = 4*k4 + kk;
        float j2c[6];
        #pragma unroll
        for (int jj = 0; jj < 6; ++jj) j2c[jj] = J2_s[k*24 + c0 + jj];
        #pragma unroll
        for (int j = 0; j < 5; ++j){
          float wv = WET[k*320 + l + 64*j];   // cols 300..319 are zero-padded
          #pragma unroll
          for (int jj = 0; jj < 6; ++jj) acc2[j][jj] = fmaf(wv, j2c[jj], acc2[j][jj]);
        }
      }
    }
    // dlo (safe before barrier: disjoint from J2_s)
    #pragma unroll
    for (int j = 0; j < 5; ++j){
      int r = l + 64*j;
      if (r >= 24 && r < 300){
        int o = r - 24;
        #pragma unroll
        for (int jj = 0; jj < 6; ++jj) dlo_s[o*24 + c0 + jj] = acc2[j][jj];
      }
    }
    __syncthreads();   // all waves done reading J2_s
    if (l < 24){       // dld aliased into J2_s[0,576)
      float sg = sig_s[l];
      #pragma unroll
      for (int jj = 0; jj < 6; ++jj) J2_s[l*24 + c0 + jj] = sg*acc2[0][jj];
    }
  }
  __syncthreads();

  // ---- dld_dt / dlo_dt ----
  if (t < DIM){
    float a = 0.f;
    #pragma unroll
    for (int d = 0; d < DIM; ++d) a += J2_s[t*24 + d]*qd_s[d];
    dld_dt_s[t] = a;
  }
  for (int o = t; o < NLO; o += 256){
    float a = 0.f;
    #pragma unroll
    for (int d = 0; d < DIM; ++d) a += dlo_s[o*24 + d]*qd_s[d];
    dlo_dt_s[o] = a;
  }
  __syncthreads();
  // ---- dLdt (aliased into J2_s[576,1152)) ----
  float* dLdt = J2_s + 576;
  for (int idx = t; idx < DIM*DIM; idx += 256){
    int r = idx/DIM, cc = idx%DIM; float v = 0.f;
    if (r == cc) v = dld_dt_s[r]; else if (r > cc) v = dlo_dt_s[r*(r-1)/2 + cc];
    dLdt[idx] = v;
  }
  __syncthreads();
  if (t < DIM){
    float a = 0.f;
    #pragma unroll
    for (int j = 0; j < DIM; ++j) a += qd_s[j]*dLdt[j*24 + t];
    w1_s[t] = a;
  }
  __syncthreads();
  // ---- c ----
  if (t < DIM){
    const int i = t;
    const float* Lrow = rec + 64 + i*24;
    float cs = 0.f;
    #pragma unroll
    for (int k = 0; k < DIM; ++k) cs += Lrow[k]*w1_s[k] + dLdt[i*24+k]*u_s[k];
    const int m = (n*DIM + i) & (NSAMP-1);   // faithful cross-sample index
    const float* um  = REC + (size_t)m*REC_STRIDE + 40;
    const float* qdm = q_dot + m*DIM;
    const float* vb  = dlo_s + i*NLO;        // faithful flat reinterpretation
    float quad = 0.f;
    for (int c2 = 0; c2 < DIM; ++c2){
      float v = qdm[c2]*J2_s[c2*24 + i];     // dld_dq[n, c2, i]
      for (int r = c2+1; r < DIM; ++r) v += qdm[r]*vb[r*(r-1)/2 + c2];
      quad += um[c2]*v;
    }
    out[C_OFF + n*DIM + i] = cs - quad;
  }
}

extern "C" void kernel_launch(void* const* d_in, const int* in_sizes, int n_in,
                              void* d_out, int out_size, void* d_ws, size_t ws_size,
                              hipStream_t stream)
{
  const float* q   = (const float*)d_in[0];
  const float* qd  = (const float*)d_in[1];
  const float* W1  = (const float*)d_in[2];
  const float* b1  = (const float*)d_in[3];
  const float* W2  = (const float*)d_in[4];
  const float* b2  = (const float*)d_in[5];
  const float* WG  = (const float*)d_in[6];
  const float* bG  = (const float*)d_in[7];
  const float* WLd = (const float*)d_in[8];
  const float* bLd = (const float*)d_in[9];
  const float* WLo = (const float*)d_in[10];
  const float* bLo = (const float*)d_in[11];
  float* out = (float*)d_out;
  float* ws  = (float*)d_ws;

  k0_prep<<<128, 256, 0, stream>>>(W1, W2, WG, WLd, WLo, ws);
  k1_fwd<<<NSAMP, 256, 0, stream>>>(q, qd, b1, b2, bG, bLd, bLo, ws, out);
  k2_jac<<<NSAMP, 256, 0, stream>>>(qd, W1, ws, out);
}

// Round 3
// 290.434 us; speedup vs baseline: 3.7731x; 2.4448x over previous
//
#include <hip/hip_runtime.h>
#include <math.h>

#define DIM 24
#define HID 256
#define NLO 276
#define NSAMP 4096
// output layout: M [4096*576] | c [4096*24] | g [4096*24]
#define C_OFF 2359296
#define G_OFF 2457600

// workspace layout (float offsets)
#define OFF_W2T  0          // [k*256+i] = W2[i,k]                    65536
#define OFF_WHT  65536      // [k*328+c] heads^T (Ld|G|Lo)            83968
#define OFF_W1T  149504     // [d*256+i] = W1[i,d]                    6144
#define OFF_W2FH 155648     // W2 frag-ordered bf16 hi (65536 bf16)   32768 f
#define OFF_W2FL 188416     // W2 frag-ordered bf16 lo                32768 f
#define OFF_WEFH 221184     // [WLd;WLo;0] frag-ordered hi (81920)    40960 f
#define OFF_WEFL 262144     // lo                                     40960 f
#define OFF_REC  303104     // per-sample record, 640 floats:
                            // [0..16) msk1/msk2 u32, [16..40) sig, [40..64) u, [64..640) L
#define REC_STRIDE 640

typedef __attribute__((ext_vector_type(8))) short bf16x8;
typedef __attribute__((ext_vector_type(4))) float f32x4;

__device__ __forceinline__ float leaky(float x){ return x > 0.f ? x : 0.01f*x; }
__device__ __forceinline__ unsigned short f2b(float f){           // fp32 -> bf16 RNE
  unsigned u = __float_as_uint(f);
  return (unsigned short)((u + 0x7FFFu + ((u >> 16) & 1u)) >> 16);
}
__device__ __forceinline__ float b2f(unsigned short h){ return __uint_as_float(((unsigned)h) << 16); }

// ---------------- Kernel 0: weight transposes + bf16 fragment packing ----------------
__global__ __launch_bounds__(256) void k0_prep(
    const float* __restrict__ W1, const float* __restrict__ W2,
    const float* __restrict__ WG, const float* __restrict__ WLd,
    const float* __restrict__ WLo, float* __restrict__ ws)
{
  const int tid = blockIdx.x*256 + threadIdx.x;
  const int nth = gridDim.x*256;
  for (int f = tid; f < 65536; f += nth){ int k = f>>8, i = f&255; ws[OFF_W2T+f] = W2[i*256+k]; }
  for (int f = tid; f < 83968; f += nth){
    int k = f/328, c = f%328; float v = 0.f;
    if (c < 24) v = WLd[c*256+k];
    else if (c < 48) v = WG[(c-24)*256+k];
    else if (c < 324) v = WLo[(c-48)*256+k];
    ws[OFF_WHT+f] = v;
  }
  for (int f = tid; f < 6144; f += nth){ int d = f>>8, i = f&255; ws[OFF_W1T+f] = W1[i*24+d]; }
  // fragment order for 16x16x32 MFMA A-operand: elem((mt,kb,lane,j)):
  //   m = mt*16 + (lane&15), k = kb*32 + (lane>>4)*8 + j ; flat = ((mt*8+kb)*64+lane)*8+j
  unsigned short* W2FH = (unsigned short*)(ws + OFF_W2FH);
  unsigned short* W2FL = (unsigned short*)(ws + OFF_W2FL);
  for (int e = tid; e < 65536; e += nth){
    int j = e&7, l = (e>>3)&63, kb = (e>>9)&7, mt = e>>12;
    int m = mt*16 + (l&15), k = kb*32 + ((l>>4)&3)*8 + j;
    float v = W2[m*256 + k];
    unsigned short h = f2b(v);
    W2FH[e] = h; W2FL[e] = f2b(v - b2f(h));
  }
  unsigned short* WEFH = (unsigned short*)(ws + OFF_WEFH);
  unsigned short* WEFL = (unsigned short*)(ws + OFF_WEFL);
  for (int e = tid; e < 81920; e += nth){   // 20 M-tiles (rows 300..319 zero)
    int j = e&7, l = (e>>3)&63, kb = (e>>9)&7, mt = e>>12;
    int r = mt*16 + (l&15), k = kb*32 + ((l>>4)&3)*8 + j;
    float v = 0.f;
    if (r < 24) v = WLd[r*256+k]; else if (r < 300) v = WLo[(r-24)*256+k];
    unsigned short h = f2b(v);
    WEFH[e] = h; WEFL[e] = f2b(v - b2f(h));
  }
}

// ---------------- Kernel 1: forward trunk + heads + L + M + g + u + record ----------------
// (unchanged from R2 — known correct; MFMA-ize next round)
__global__ __launch_bounds__(256) void k1_fwd(
    const float* __restrict__ q, const float* __restrict__ qd,
    const float* __restrict__ b1, const float* __restrict__ b2,
    const float* __restrict__ bG, const float* __restrict__ bLd,
    const float* __restrict__ bLo, float* __restrict__ ws,
    float* __restrict__ out)
{
  const int n = blockIdx.x, t = threadIdx.x;
  const int w = t >> 6, l = t & 63;
  const float* W2T = ws + OFF_W2T;
  const float* WHT = ws + OFF_WHT;
  const float* W1T = ws + OFF_W1T;
  float* rec = ws + OFF_REC + (size_t)n*REC_STRIDE;

  __shared__ float q_s[DIM], qd_s[DIM], h1_s[HID], h2_s[HID], h3_s[DIM], lo_s[NLO], L_s[DIM*DIM];
  if (t < DIM){ q_s[t] = q[n*DIM+t]; qd_s[t] = qd[n*DIM+t]; }
  __syncthreads();
  {
    float s = b1[t];
    #pragma unroll
    for (int d = 0; d < DIM; ++d) s += W1T[d*256 + t]*q_s[d];
    unsigned long long b = __ballot(s > 0.f);
    if (l == 0){ ((unsigned*)rec)[2*w] = (unsigned)b; ((unsigned*)rec)[2*w+1] = (unsigned)(b >> 32); }
    h1_s[t] = leaky(s);
  }
  __syncthreads();
  {
    float s = b2[t];
    const float4* h = (const float4*)h1_s;
    for (int k4 = 0; k4 < HID/4; ++k4){
      float4 hv = h[k4];
      int k = 4*k4;
      s += W2T[(k+0)*256+t]*hv.x + W2T[(k+1)*256+t]*hv.y
         + W2T[(k+2)*256+t]*hv.z + W2T[(k+3)*256+t]*hv.w;
    }
    unsigned long long b = __ballot(s > 0.f);
    if (l == 0){ ((unsigned*)rec)[8+2*w] = (unsigned)b; ((unsigned*)rec)[8+2*w+1] = (unsigned)(b >> 32); }
    h2_s[t] = leaky(s);
  }
  __syncthreads();
  for (int c = t; c < 324; c += 256){
    float acc = 0.f;
    const float4* h = (const float4*)h2_s;
    for (int k4 = 0; k4 < HID/4; ++k4){
      float4 hv = h[k4];
      int k = 4*k4;
      acc += WHT[(k+0)*328+c]*hv.x + WHT[(k+1)*328+c]*hv.y
           + WHT[(k+2)*328+c]*hv.z + WHT[(k+3)*328+c]*hv.w;
    }
    if (c < 24){
      acc += bLd[c];
      h3_s[c] = acc;
      rec[16 + c] = 1.f/(1.f + expf(-acc));
    } else if (c < 48){
      out[G_OFF + n*DIM + (c-24)] = acc + bG[c-24];
    } else {
      lo_s[c-48] = acc + bLo[c-48];
    }
  }
  __syncthreads();
  for (int idx = t; idx < DIM*DIM; idx += 256){
    int r = idx/DIM, c = idx%DIM; float v = 0.f;
    if (r == c){ float x = h3_s[r]; v = fmaxf(x, 0.f) + log1pf(expf(-fabsf(x))); }
    else if (r > c) v = lo_s[r*(r-1)/2 + c];
    L_s[idx] = v; rec[64 + idx] = v;
  }
  __syncthreads();
  for (int idx = t; idx < DIM*DIM; idx += 256){
    int r = idx/DIM, c = idx%DIM, km = min(r, c);
    float acc = (r == c) ? 1e-9f : 0.f;
    for (int k = 0; k <= km; ++k) acc += L_s[r*DIM+k]*L_s[c*DIM+k];
    out[n*DIM*DIM + idx] = acc;
  }
  if (t < DIM){
    float acc = 0.f;
    for (int r = t; r < DIM; ++r) acc += qd_s[r]*L_s[r*DIM+t];
    rec[40 + t] = acc;
  }
}

// ---------------- Kernel 2: MFMA Jacobian chain + c (2 samples/block) ----------------
// Stage D: C1[256x48] = W2 @ (dR1⊙W1)  -> scale rows by dR2 -> J2 (bf16-split in LDS)
// Stage E: E[320x48]  = [WLd;WLo;0] @ J2 -> dld (sig-scaled) / dlo -> scalar tail -> c
__global__ __launch_bounds__(256, 2) void k2_jac(
    const float* __restrict__ q_dot, const float* __restrict__ W1g,
    float* __restrict__ ws, float* __restrict__ out)
{
  const int n0 = blockIdx.x*2, t = threadIdx.x;
  const int w = t >> 6, l = t & 63;
  const int l15 = l & 15, l4g = (l >> 4) & 3;
  const float* REC = ws + OFF_REC;

  // LDS pool overlays: [BH|BL] (K-loops) -> [JH|JL] -> [dlo2 | dLdt2 | dlo_dt2]
  __shared__ __align__(16) char pool[59808];
  __shared__ float dld2[2][576];
  __shared__ float qd2[2][24], u2[2][24], sig2[2][24], dld_dt2[2][24], w12[2][24];
  __shared__ unsigned msk[2][16];
  unsigned short* BH = (unsigned short*)pool;              // [48][264] bf16, k-contig
  unsigned short* BL = (unsigned short*)(pool + 25344);
  float* dlo2   = (float*)pool;                            // [2][6624]  (52992 B)
  float* dLdt2  = (float*)(pool + 52992);                  // [2][576]
  float* dlo_dt2= (float*)(pool + 57600);                  // [2][276]

  if (t < 32) msk[t>>4][t&15] = ((const unsigned*)(REC + (size_t)(n0 + (t>>4))*REC_STRIDE))[t&15];
  if (t < 48){
    int s = t/24, i = t%24;
    const float* rc = REC + (size_t)(n0+s)*REC_STRIDE;
    sig2[s][i] = rc[16+i]; u2[s][i] = rc[40+i]; qd2[s][i] = q_dot[(n0+s)*24+i];
  }
  __syncthreads();

  // ---- build Bd = dR1 ⊙ W1 (split) : thread t owns k=t, loops cols ----
  {
    float w1r[24];
    #pragma unroll
    for (int d = 0; d < 24; ++d) w1r[d] = W1g[t*24 + d];
    float dr0 = ((msk[0][t>>5] >> (t&31)) & 1u) ? 1.f : -0.01f;
    float dr1 = ((msk[1][t>>5] >> (t&31)) & 1u) ? 1.f : -0.01f;
    #pragma unroll
    for (int c = 0; c < 48; ++c){
      int s = c >= 24, d = c - 24*s;
      float f = (s ? dr1 : dr0) * w1r[d];
      unsigned short h = f2b(f);
      BH[c*264 + t] = h;
      BL[c*264 + t] = f2b(f - b2f(h));
    }
  }
  __syncthreads();

  // ---- Stage D K-loop: wave w -> M-tiles {4w..4w+3} x N-tiles {0,1,2} ----
  f32x4 accD[4][3];
  #pragma unroll
  for (int i = 0; i < 4; ++i)
    #pragma unroll
    for (int nt = 0; nt < 3; ++nt) accD[i][nt] = (f32x4){0.f,0.f,0.f,0.f};
  {
    const bf16x8* AHp = (const bf16x8*)(ws + OFF_W2FH);
    const bf16x8* ALp = (const bf16x8*)(ws + OFF_W2FL);
    for (int kb = 0; kb < 8; ++kb){
      bf16x8 AH[4], AL[4], BHf[3], BLf[3];
      #pragma unroll
      for (int i = 0; i < 4; ++i){
        int mt = 4*w + i;
        AH[i] = AHp[(mt*8+kb)*64 + l];
        AL[i] = ALp[(mt*8+kb)*64 + l];
      }
      #pragma unroll
      for (int nt = 0; nt < 3; ++nt){
        int off = (nt*16 + l15)*264 + kb*32 + l4g*8;
        BHf[nt] = *(const bf16x8*)(BH + off);
        BLf[nt] = *(const bf16x8*)(BL + off);
      }
      #pragma unroll
      for (int i = 0; i < 4; ++i)
        #pragma unroll
        for (int nt = 0; nt < 3; ++nt){
          accD[i][nt] = __builtin_amdgcn_mfma_f32_16x16x32_bf16(AH[i], BHf[nt], accD[i][nt], 0, 0, 0);
          accD[i][nt] = __builtin_amdgcn_mfma_f32_16x16x32_bf16(AH[i], BLf[nt], accD[i][nt], 0, 0, 0);
          accD[i][nt] = __builtin_amdgcn_mfma_f32_16x16x32_bf16(AL[i], BHf[nt], accD[i][nt], 0, 0, 0);
        }
    }
  }
  __syncthreads();   // all waves done reading Bd

  // ---- epilogue D: scale by dR2, split, store J2 (col-major, k-contig) over Bd ----
  {
    unsigned short* JH = BH; unsigned short* JL = BL;
    #pragma unroll
    for (int i = 0; i < 4; ++i){
      int mt = 4*w + i;
      int m0 = mt*16 + 4*l4g;
      int bb = m0 & 31;
      #pragma unroll
      for (int nt = 0; nt < 3; ++nt){
        int c = nt*16 + l15;
        int s = c >= 24;
        unsigned word = msk[s][8 + (mt>>1)];
        unsigned short hs[4], ls[4];
        #pragma unroll
        for (int r = 0; r < 4; ++r){
          float sc = ((word >> (bb + r)) & 1u) ? 1.f : -0.01f;
          float v = sc * accD[i][nt][r];
          hs[r] = f2b(v); ls[r] = f2b(v - b2f(hs[r]));
        }
        *(uint2*)(JH + c*264 + m0) = make_uint2((unsigned)hs[0] | ((unsigned)hs[1]<<16),
                                                (unsigned)hs[2] | ((unsigned)hs[3]<<16));
        *(uint2*)(JL + c*264 + m0) = make_uint2((unsigned)ls[0] | ((unsigned)ls[1]<<16),
                                                (unsigned)ls[2] | ((unsigned)ls[3]<<16));
      }
    }
  }
  __syncthreads();

  // ---- Stage E K-loop: wave w -> M-tiles {5w..5w+4} x N-tiles {0,1,2} ----
  f32x4 accE[5][3];
  #pragma unroll
  for (int i = 0; i < 5; ++i)
    #pragma unroll
    for (int nt = 0; nt < 3; ++nt) accE[i][nt] = (f32x4){0.f,0.f,0.f,0.f};
  {
    const bf16x8* AHp = (const bf16x8*)(ws + OFF_WEFH);
    const bf16x8* ALp = (const bf16x8*)(ws + OFF_WEFL);
    for (int kb = 0; kb < 8; ++kb){
      bf16x8 AH[5], AL[5], BHf[3], BLf[3];
      #pragma unroll
      for (int i = 0; i < 5; ++i){
        int mt = 5*w + i;
        AH[i] = AHp[(mt*8+kb)*64 + l];
        AL[i] = ALp[(mt*8+kb)*64 + l];
      }
      #pragma unroll
      for (int nt = 0; nt < 3; ++nt){
        int off = (nt*16 + l15)*264 + kb*32 + l4g*8;
        BHf[nt] = *(const bf16x8*)(BH + off);
        BLf[nt] = *(const bf16x8*)(BL + off);
      }
      #pragma unroll
      for (int i = 0; i < 5; ++i)
        #pragma unroll
        for (int nt = 0; nt < 3; ++nt){
          accE[i][nt] = __builtin_amdgcn_mfma_f32_16x16x32_bf16(AH[i], BHf[nt], accE[i][nt], 0, 0, 0);
          accE[i][nt] = __builtin_amdgcn_mfma_f32_16x16x32_bf16(AH[i], BLf[nt], accE[i][nt], 0, 0, 0);
          accE[i][nt] = __builtin_amdgcn_mfma_f32_16x16x32_bf16(AL[i], BHf[nt], accE[i][nt], 0, 0, 0);
        }
    }
  }
  __syncthreads();   // all waves done reading J2

  // ---- epilogue E: scatter dld (sig-scaled) / dlo to fp32 LDS (over J2) ----
  #pragma unroll
  for (int i = 0; i < 5; ++i){
    int mt = 5*w + i;
    #pragma unroll
    for (int nt = 0; nt < 3; ++nt){
      int c = nt*16 + l15;
      int s = c >= 24, d = c - 24*s;
      #pragma unroll
      for (int r = 0; r < 4; ++r){
        int re = mt*16 + 4*l4g + r;
        float v = accE[i][nt][r];
        if (re < 24) dld2[s][re*24 + d] = sig2[s][re]*v;
        else if (re < 300) dlo2[s*6624 + (re-24)*24 + d] = v;
      }
    }
  }
  __syncthreads();

  // ---- scalar tail (same as verified R2, per sample) ----
  for (int o2 = t; o2 < 2*NLO; o2 += 256){
    int s = o2 / NLO, o = o2 % NLO;
    float a = 0.f;
    #pragma unroll
    for (int d = 0; d < 24; ++d) a += dlo2[s*6624 + o*24 + d]*qd2[s][d];
    dlo_dt2[s*NLO + o] = a;
  }
  if (t < 48){
    int s = t/24, i = t%24;
    float a = 0.f;
    #pragma unroll
    for (int d = 0; d < 24; ++d) a += dld2[s][i*24+d]*qd2[s][d];
    dld_dt2[s][i] = a;
  }
  __syncthreads();
  for (int idx = t; idx < 1152; idx += 256){
    int s = idx/576, e = idx%576, r = e/24, cc = e%24;
    float v = 0.f;
    if (r == cc) v = dld_dt2[s][r]; else if (r > cc) v = dlo_dt2[s*NLO + r*(r-1)/2 + cc];
    dLdt2[s*576 + e] = v;
  }
  __syncthreads();
  if (t < 48){
    int s = t/24, i = t%24;
    float a = 0.f;
    #pragma unroll
    for (int j = 0; j < 24; ++j) a += qd2[s][j]*dLdt2[s*576 + j*24 + i];
    w12[s][i] = a;
  }
  __syncthreads();
  if (t < 48){
    int s = t/24, i = t%24;
    int n = n0 + s;
    const float* Lrow = REC + (size_t)n*REC_STRIDE + 64 + i*24;
    float cs = 0.f;
    #pragma unroll
    for (int k = 0; k < 24; ++k) cs += Lrow[k]*w12[s][k] + dLdt2[s*576 + i*24 + k]*u2[s][k];
    const int m = (n*24 + i) & (NSAMP-1);         // faithful cross-sample index
    const float* um  = REC + (size_t)m*REC_STRIDE + 40;
    const float* qdm = q_dot + m*24;
    const float* vb  = dlo2 + s*6624 + i*NLO;     // faithful flat reinterpretation
    float quad = 0.f;
    for (int c2 = 0; c2 < 24; ++c2){
      float v = qdm[c2]*dld2[s][c2*24 + i];
      for (int r = c2+1; r < 24; ++r) v += qdm[r]*vb[r*(r-1)/2 + c2];
      quad += um[c2]*v;
    }
    out[C_OFF + n*24 + i] = cs - quad;
  }
}

extern "C" void kernel_launch(void* const* d_in, const int* in_sizes, int n_in,
                              void* d_out, int out_size, void* d_ws, size_t ws_size,
                              hipStream_t stream)
{
  const float* q   = (const float*)d_in[0];
  const float* qd  = (const float*)d_in[1];
  const float* W1  = (const float*)d_in[2];
  const float* b1  = (const float*)d_in[3];
  const float* W2  = (const float*)d_in[4];
  const float* b2  = (const float*)d_in[5];
  const float* WG  = (const float*)d_in[6];
  const float* bG  = (const float*)d_in[7];
  const float* WLd = (const float*)d_in[8];
  const float* bLd = (const float*)d_in[9];
  const float* WLo = (const float*)d_in[10];
  const float* bLo = (const float*)d_in[11];
  float* out = (float*)d_out;
  float* ws  = (float*)d_ws;

  k0_prep<<<256, 256, 0, stream>>>(W1, W2, WG, WLd, WLo, ws);
  k1_fwd<<<NSAMP, 256, 0, stream>>>(q, qd, b1, b2, bG, bLd, bLo, ws, out);
  k2_jac<<<NSAMP/2, 256, 0, stream>>>(qd, W1, ws, out);
}